// Round 5
// baseline (164.679 us; speedup 1.0000x reference)
//
#include <hip/hip_runtime.h>
#include <hip/hip_bf16.h>

#define B_ 2
#define N_ 512
#define DS_ 384
#define DP_ 128
#define H_ 16
#define DH_ 64
#define DI_ 1024
#define MAXSEQ 2048
#define PAD 8

typedef float f32x4 __attribute__((ext_vector_type(4)));
typedef short bf16x8 __attribute__((ext_vector_type(8)));

__device__ __forceinline__ unsigned short f2b(float f) {
    unsigned int u = __builtin_bit_cast(unsigned int, f);
    u += 0x7FFFu + ((u >> 16) & 1u);
    return (unsigned short)(u >> 16);
}
__device__ __forceinline__ float b2f(unsigned short s) {
    unsigned int u = ((unsigned int)s) << 16;
    return __builtin_bit_cast(float, u);
}

// ---------------- all weight transposes in one launch ----------------------
__global__ __launch_bounds__(256) void k_transpose_all(const float* __restrict__ wq,
                                                       const float* __restrict__ wk,
                                                       const float* __restrict__ wv,
                                                       const float* __restrict__ wg,
                                                       const float* __restrict__ wo,
                                                       unsigned short* __restrict__ Wt,
                                                       unsigned short* __restrict__ Wot) {
    __shared__ float tile[32][33];
    int z = blockIdx.z;
    const float* in;
    unsigned short* out;
    int R, C;
    if (z < 4) {
        in = (z == 0) ? wq : (z == 1) ? wk : (z == 2) ? wv : wg;
        out = Wt + (long)z * 1024 * 384;
        R = 384; C = 1024;
    } else {
        in = wo; out = Wot; R = 1024; C = 384;
    }
    int c0 = blockIdx.x * 32, r0 = blockIdx.y * 32;
    if (c0 >= C || r0 >= R) return;
    int tx = threadIdx.x & 31, ty = threadIdx.x >> 5;
    #pragma unroll
    for (int i = ty; i < 32; i += 8)
        tile[i][tx] = in[(long)(r0 + i) * C + (c0 + tx)];
    __syncthreads();
    #pragma unroll
    for (int i = ty; i < 32; i += 8)
        out[(long)(c0 + i) * R + (r0 + tx)] = f2b(tile[tx][i]);
}

// ---------------- bias: LN(pairwise) @ w_bias + abb -> bf16 [b][h][i][j] ----
// v3: MFMA for the 16-head dot (replaces 640 LDS reads/thread with 8 MFMA/wave).
// Block = 128 rows (one (b,i), 128 consecutive j). Grid = 4096.
__global__ __launch_bounds__(256) void k_bias(const float* __restrict__ pw,
                                              const float* __restrict__ gamma,
                                              const float* __restrict__ beta,
                                              const float* __restrict__ wb,
                                              const float* __restrict__ abb,
                                              unsigned short* __restrict__ biasP) {
    __shared__ unsigned short Xb[128][136];  // 34.8 KB bf16 rows, +8 pad
    __shared__ unsigned short Gh[16][136];   // 4.4 KB  Gh[h][d] = gamma[d]*wb[d][h]
    __shared__ float rowsum[128], rowsumsq[128], ab[128];
    __shared__ float Ssum[H_], Tsum[H_];
    int t = threadIdx.x;
    long p0 = (long)blockIdx.x * 128;
    int i_blk = (int)((p0 >> 9) & (N_ - 1));
    int j0 = (int)(p0 & (N_ - 1));

    // G^T into LDS (bf16)
    for (int idx = t; idx < DP_ * H_; idx += 256) {
        int d = idx >> 4, h = idx & 15;
        Gh[h][d] = f2b(gamma[d] * wb[idx]);
    }
    if (t < 32) {
        int h = t & 15;
        const float* src = (t >= 16) ? beta : gamma;
        float s = 0.f;
        for (int d = 0; d < DP_; ++d) s = fmaf(src[d], wb[d * H_ + h], s);
        if (t >= 16) Tsum[h] = s; else Ssum[h] = s;
    }
    if (t < 128) ab[t] = abb[(long)i_blk * MAXSEQ + j0 + t];

    // stage 128 rows x 128 feats: fp32 -> bf16, stats via 32-lane shuffle reduce
    #pragma unroll
    for (int it = 0; it < 16; ++it) {
        int flat = it * 256 + t;            // row-major float4 index
        int row = flat >> 5, c = flat & 31; // 32 float4 per row
        float4 v = *(const float4*)(pw + ((p0 + row) << 7) + c * 4);
        float ps = v.x + v.y + v.z + v.w;
        float pq = fmaf(v.x, v.x, fmaf(v.y, v.y, fmaf(v.z, v.z, v.w * v.w)));
        #pragma unroll
        for (int off = 1; off < 32; off <<= 1) {
            ps += __shfl_xor(ps, off);
            pq += __shfl_xor(pq, off);
        }
        if ((t & 31) == 0) { rowsum[row] = ps; rowsumsq[row] = pq; }
        ushort4 xb;
        xb.x = f2b(v.x); xb.y = f2b(v.y); xb.z = f2b(v.z); xb.w = f2b(v.w);
        *(ushort4*)&Xb[row][c * 4] = xb;
    }
    __syncthreads();

    int w = t >> 6, lane = t & 63;
    int lane15 = lane & 15, kg = lane >> 4;
    // B fragments (heads), hoisted
    bf16x8 gb[4];
    #pragma unroll
    for (int kk = 0; kk < 4; ++kk)
        gb[kk] = *(const bf16x8*)&Gh[lane15][kk * 32 + kg * 8];
    float sh = Ssum[lane15], th = Tsum[lane15];

    #pragma unroll
    for (int m = 0; m < 2; ++m) {
        int rbase = w * 32 + m * 16;        // wave w owns rows w*32 .. +32
        f32x4 acc = {};
        #pragma unroll
        for (int kk = 0; kk < 4; ++kk) {
            bf16x8 a = *(const bf16x8*)&Xb[rbase + lane15][kk * 32 + kg * 8];
            acc = __builtin_amdgcn_mfma_f32_16x16x32_bf16(a, gb[kk], acc, 0, 0, 0);
        }
        // lane holds col h=lane15, rows rbase + kg*4 + r
        int lr0 = rbase + kg * 4;
        float4 rs = *(const float4*)&rowsum[lr0];
        float4 rq = *(const float4*)&rowsumsq[lr0];
        float4 av = *(const float4*)&ab[lr0];
        long p = p0 + lr0;
        long bb = p >> 18;
        int h = lane15;
        unsigned short* outp = biasP + (((bb * H_ + h) * N_ + i_blk) * N_) + j0 + (lr0 & 127);
        ushort4 res;
        {
            float mu = rs.x * (1.f / DP_);
            float var = fmaf(rq.x, 1.f / DP_, -mu * mu);
            res.x = f2b(fmaf(rsqrtf(var + 1e-5f), acc[0] - mu * sh, th + av.x));
            mu = rs.y * (1.f / DP_);
            var = fmaf(rq.y, 1.f / DP_, -mu * mu);
            res.y = f2b(fmaf(rsqrtf(var + 1e-5f), acc[1] - mu * sh, th + av.y));
            mu = rs.z * (1.f / DP_);
            var = fmaf(rq.z, 1.f / DP_, -mu * mu);
            res.z = f2b(fmaf(rsqrtf(var + 1e-5f), acc[2] - mu * sh, th + av.z));
            mu = rs.w * (1.f / DP_);
            var = fmaf(rq.w, 1.f / DP_, -mu * mu);
            res.w = f2b(fmaf(rsqrtf(var + 1e-5f), acc[3] - mu * sh, th + av.w));
        }
        *(ushort4*)outp = res;
    }
}

// ---------------- QKVG projection GEMM (M=1024, N=4096, K=384) --------------
// Q is pre-scaled by 0.125 (folded attention scale).
__global__ __launch_bounds__(256) void k_proj(const float* __restrict__ X,
                                              const unsigned short* __restrict__ Wt,
                                              unsigned short* __restrict__ Qb,
                                              unsigned short* __restrict__ Kb,
                                              unsigned short* __restrict__ Vt,
                                              unsigned short* __restrict__ Xg) {
    __shared__ unsigned short As[128][64 + PAD];
    __shared__ unsigned short Bs[128][64 + PAD];
    int m0 = blockIdx.x * 128;
    int n0 = blockIdx.y * 128;
    int t = threadIdx.x;
    int wave = t >> 6, lane = t & 63;
    int wr = wave >> 1, wc = wave & 1;
    int lane15 = lane & 15, kg = lane >> 4;
    f32x4 acc[4][4] = {};
    for (int k0 = 0; k0 < DS_; k0 += 64) {
        __syncthreads();
        {
            int r = t >> 1, half = t & 1;
            const float4* src = (const float4*)(X + (long)(m0 + r) * DS_ + k0 + half * 32);
            unsigned short* dst = &As[r][half * 32];
            #pragma unroll
            for (int ii = 0; ii < 8; ++ii) {
                float4 v = src[ii];
                dst[ii * 4 + 0] = f2b(v.x); dst[ii * 4 + 1] = f2b(v.y);
                dst[ii * 4 + 2] = f2b(v.z); dst[ii * 4 + 3] = f2b(v.w);
            }
            const uint4* wsrc = (const uint4*)(Wt + (long)(n0 + r) * DS_ + k0 + half * 32);
            uint4* wdst = (uint4*)&Bs[r][half * 32];
            wdst[0] = wsrc[0]; wdst[1] = wsrc[1]; wdst[2] = wsrc[2]; wdst[3] = wsrc[3];
        }
        __syncthreads();
        #pragma unroll
        for (int ks = 0; ks < 2; ++ks) {
            bf16x8 a[4], bb[4];
            #pragma unroll
            for (int mf = 0; mf < 4; ++mf)
                a[mf] = *(const bf16x8*)&As[wr * 64 + mf * 16 + lane15][ks * 32 + kg * 8];
            #pragma unroll
            for (int nf = 0; nf < 4; ++nf)
                bb[nf] = *(const bf16x8*)&Bs[wc * 64 + nf * 16 + lane15][ks * 32 + kg * 8];
            #pragma unroll
            for (int mf = 0; mf < 4; ++mf)
                #pragma unroll
                for (int nf = 0; nf < 4; ++nf)
                    acc[mf][nf] = __builtin_amdgcn_mfma_f32_16x16x32_bf16(a[mf], bb[nf], acc[mf][nf], 0, 0, 0);
        }
    }
    int p = n0 >> 10;                 // which projection (q,k,v,g)
    int lgrp = lane >> 4;
    #pragma unroll
    for (int mf = 0; mf < 4; ++mf) {
        #pragma unroll
        for (int nf = 0; nf < 4; ++nf) {
            int col = n0 + wc * 64 + nf * 16 + lane15;
            int ch = col & 1023;
            int h = ch >> 6, dh = ch & 63;
            int row0 = m0 + wr * 64 + mf * 16 + lgrp * 4;
            if (p == 0 || p == 1) {
                unsigned short* base = (p == 0) ? Qb : Kb;
                float scl = (p == 0) ? 0.125f : 1.0f;
                #pragma unroll
                for (int r = 0; r < 4; ++r) {
                    int row = row0 + r;
                    int b = row >> 9, n = row & 511;
                    base[(((long)(b * 16 + h)) * 512 + n) * 64 + dh] = f2b(acc[mf][nf][r] * scl);
                }
            } else if (p == 2) {
                int b = row0 >> 9, n = row0 & 511;
                ushort4 v;
                v.x = f2b(acc[mf][nf][0]); v.y = f2b(acc[mf][nf][1]);
                v.z = f2b(acc[mf][nf][2]); v.w = f2b(acc[mf][nf][3]);
                *(ushort4*)&Vt[(((long)(b * 16 + h)) * 64 + dh) * 512 + n] = v;
            } else {
                #pragma unroll
                for (int r = 0; r < 4; ++r) {
                    int row = row0 + r;
                    Xg[(long)row * 1024 + ch] = f2b(acc[mf][nf][r]);
                }
            }
        }
    }
}

// ---------------- fused flash attention: S=Q@K^T+bias, softmax, P@V, gate ---
// grid (8 i-blocks, 32 bh), 256 threads (4 waves, wave w owns i-rows w*16..+16)
__global__ __launch_bounds__(256) void k_flash(const unsigned short* __restrict__ Qb,
                                               const unsigned short* __restrict__ Kb,
                                               const unsigned short* __restrict__ Vt,
                                               const unsigned short* __restrict__ biasP,
                                               const unsigned short* __restrict__ Xg,
                                               unsigned short* __restrict__ Og) {
    __shared__ unsigned short Kt[64][72];    // [j][dh]
    __shared__ unsigned short Vs[64][72];    // [dh][j]
    __shared__ unsigned short Bt[64][72];    // [i][j] bias tile
    __shared__ unsigned short Ps[4][16][72]; // per-wave P [i][j]
    int bh = blockIdx.y;
    int b = bh >> 4, h = bh & 15;
    int i0 = blockIdx.x * 64;
    int t = threadIdx.x, w = t >> 6, lane = t & 63;
    int lane15 = lane & 15, lgrp = lane >> 4;

    // Q fragments (B-operand), row i = i0 + w*16 + lane15, pre-scaled by 0.125
    bf16x8 qf[2];
    #pragma unroll
    for (int kk = 0; kk < 2; ++kk)
        qf[kk] = *(const bf16x8*)&Qb[((long)bh * 512 + i0 + w * 16 + lane15) * 64 + kk * 32 + lgrp * 8];

    float m_run = -1e30f, l_run = 0.f;
    f32x4 o[4] = {};   // o[nf][r] = O[i0+w*16+lgrp*4+r][nf*16+lane15]

    for (int jt = 0; jt < 8; ++jt) {
        int j0 = jt * 64;
        __syncthreads();   // previous tile fully consumed
        #pragma unroll
        for (int i = 0; i < 2; ++i) {
            int f = i * 256 + t;
            int r = f >> 3, c = f & 7;
            *(uint4*)&Kt[r][c * 8] = *(const uint4*)&Kb[((long)bh * 512 + j0 + r) * 64 + c * 8];
            *(uint4*)&Vs[r][c * 8] = *(const uint4*)&Vt[((long)bh * 64 + r) * 512 + j0 + c * 8];
            *(uint4*)&Bt[r][c * 8] = *(const uint4*)&biasP[(((long)bh * 512) + i0 + r) * 512 + j0 + c * 8];
        }
        __syncthreads();

        // S^T[j][i]: A = K[j][dh], B = Q[i][dh]  ->  lane holds col i=lane15, rows j
        f32x4 s[4];
        #pragma unroll
        for (int nf = 0; nf < 4; ++nf) {
            f32x4 z = {};
            #pragma unroll
            for (int kk = 0; kk < 2; ++kk) {
                bf16x8 af = *(const bf16x8*)&Kt[nf * 16 + lane15][kk * 32 + lgrp * 8];
                z = __builtin_amdgcn_mfma_f32_16x16x32_bf16(af, qf[kk], z, 0, 0, 0);
            }
            s[nf] = z;
        }
        // add bias: s[nf][r] is S[i = i0 + w*16 + lane15][j = j0 + nf*16 + lgrp*4 + r]
        #pragma unroll
        for (int nf = 0; nf < 4; ++nf)
            #pragma unroll
            for (int r = 0; r < 4; ++r)
                s[nf][r] += b2f(Bt[w * 16 + lane15][nf * 16 + lgrp * 4 + r]);

        // online softmax, lane owns row i (16 j-values per lane); reduce across
        // the 4 lanes sharing lane15 (xor 16, 32)
        float pmax = s[0][0];
        #pragma unroll
        for (int nf = 0; nf < 4; ++nf)
            #pragma unroll
            for (int r = 0; r < 4; ++r) pmax = fmaxf(pmax, s[nf][r]);
        pmax = fmaxf(pmax, __shfl_xor(pmax, 16));
        pmax = fmaxf(pmax, __shfl_xor(pmax, 32));
        float m_new = fmaxf(m_run, pmax);
        float scale = __expf(m_run - m_new);
        float psum = 0.f;
        #pragma unroll
        for (int nf = 0; nf < 4; ++nf)
            #pragma unroll
            for (int r = 0; r < 4; ++r) {
                s[nf][r] = __expf(s[nf][r] - m_new);
                psum += s[nf][r];
            }
        psum += __shfl_xor(psum, 16);
        psum += __shfl_xor(psum, 32);
        l_run = l_run * scale + psum;
        m_run = m_new;
        // rescale O (o's rows are i = lgrp*4 + r; fetch that row's scale)
        #pragma unroll
        for (int r = 0; r < 4; ++r) {
            float sc = __shfl(scale, lgrp * 4 + r);
            #pragma unroll
            for (int nf = 0; nf < 4; ++nf) o[nf][r] *= sc;
        }
        // P -> LDS (bf16), wave-private
        #pragma unroll
        for (int nf = 0; nf < 4; ++nf)
            #pragma unroll
            for (int r = 0; r < 4; ++r)
                Ps[w][lane15][nf * 16 + lgrp * 4 + r] = f2b(s[nf][r]);
        // PV: A = P[i][j] (row=lane15), B = V[dh][j] (row=lane15 of Vs)
        #pragma unroll
        for (int kk = 0; kk < 2; ++kk) {
            bf16x8 pa = *(const bf16x8*)&Ps[w][lane15][kk * 32 + lgrp * 8];
            #pragma unroll
            for (int nf = 0; nf < 4; ++nf) {
                bf16x8 vb = *(const bf16x8*)&Vs[nf * 16 + lane15][kk * 32 + lgrp * 8];
                o[nf] = __builtin_amdgcn_mfma_f32_16x16x32_bf16(pa, vb, o[nf], 0, 0, 0);
            }
        }
    }
    // epilogue: divide by l, sigmoid gate, store
    #pragma unroll
    for (int r = 0; r < 4; ++r) {
        float l_r = __shfl(l_run, lgrp * 4 + r);
        float inv = 1.f / l_r;
        long grow = (long)b * 512 + i0 + w * 16 + lgrp * 4 + r;
        #pragma unroll
        for (int nf = 0; nf < 4; ++nf) {
            int dh = nf * 16 + lane15;
            float xgv = b2f(Xg[grow * 1024 + h * 64 + dh]);
            float gate = 1.f / (1.f + __expf(-xgv));
            Og[grow * 1024 + h * 64 + dh] = f2b(o[nf][r] * inv * gate);
        }
    }
}

// ---------------- output GEMM: out = Og @ w_o (M=1024,N=384,K=1024) ---------
__global__ __launch_bounds__(256) void k_out(const unsigned short* __restrict__ Og,
                                             const unsigned short* __restrict__ Wot,
                                             float* __restrict__ out) {
    __shared__ unsigned short As[128][64 + PAD];
    __shared__ unsigned short Bs[128][64 + PAD];
    int m0 = blockIdx.x * 128, n0 = blockIdx.y * 128;
    int t = threadIdx.x, wave = t >> 6, lane = t & 63;
    int wr = wave >> 1, wc = wave & 1;
    int lane15 = lane & 15, kg = lane >> 4;
    f32x4 acc[4][4] = {};
    for (int k0 = 0; k0 < 1024; k0 += 64) {
        __syncthreads();
        {
            int r = t >> 1, half = t & 1;
            const uint4* src = (const uint4*)(Og + (long)(m0 + r) * 1024 + k0 + half * 32);
            uint4* dst = (uint4*)&As[r][half * 32];
            dst[0] = src[0]; dst[1] = src[1]; dst[2] = src[2]; dst[3] = src[3];
            const uint4* wsrc = (const uint4*)(Wot + (long)(n0 + r) * 1024 + k0 + half * 32);
            uint4* wdst = (uint4*)&Bs[r][half * 32];
            wdst[0] = wsrc[0]; wdst[1] = wsrc[1]; wdst[2] = wsrc[2]; wdst[3] = wsrc[3];
        }
        __syncthreads();
        #pragma unroll
        for (int ks = 0; ks < 2; ++ks) {
            bf16x8 a[4], bb[4];
            #pragma unroll
            for (int mf = 0; mf < 4; ++mf)
                a[mf] = *(const bf16x8*)&As[wr * 64 + mf * 16 + lane15][ks * 32 + kg * 8];
            #pragma unroll
            for (int nf = 0; nf < 4; ++nf)
                bb[nf] = *(const bf16x8*)&Bs[wc * 64 + nf * 16 + lane15][ks * 32 + kg * 8];
            #pragma unroll
            for (int mf = 0; mf < 4; ++mf)
                #pragma unroll
                for (int nf = 0; nf < 4; ++nf)
                    acc[mf][nf] = __builtin_amdgcn_mfma_f32_16x16x32_bf16(a[mf], bb[nf], acc[mf][nf], 0, 0, 0);
        }
    }
    int lgrp = lane >> 4;
    #pragma unroll
    for (int mf = 0; mf < 4; ++mf) {
        #pragma unroll
        for (int nf = 0; nf < 4; ++nf) {
            int col = n0 + wc * 64 + nf * 16 + lane15;
            int row0 = m0 + wr * 64 + mf * 16 + lgrp * 4;
            #pragma unroll
            for (int r = 0; r < 4; ++r)
                out[(long)(row0 + r) * DS_ + col] = acc[mf][nf][r];
        }
    }
}

extern "C" void kernel_launch(void* const* d_in, const int* in_sizes, int n_in,
                              void* d_out, int out_size, void* d_ws, size_t ws_size,
                              hipStream_t stream) {
    const float* single = (const float*)d_in[0];
    const float* pw     = (const float*)d_in[1];
    const float* gamma  = (const float*)d_in[2];
    const float* beta   = (const float*)d_in[3];
    const float* wb     = (const float*)d_in[4];
    const float* abb    = (const float*)d_in[5];
    const float* wq     = (const float*)d_in[6];
    const float* wk     = (const float*)d_in[7];
    const float* wv     = (const float*)d_in[8];
    const float* wg     = (const float*)d_in[9];
    const float* wo     = (const float*)d_in[10];
    float* out = (float*)d_out;
    char* ws = (char*)d_ws;

    unsigned short* SP  = (unsigned short*)(ws);                 // 16 MB bias [b][h][i][j]
    unsigned short* Qb  = (unsigned short*)(ws + 16777216);      // 2 MB (pre-scaled 0.125)
    unsigned short* Kb  = (unsigned short*)(ws + 18874368);      // 2 MB
    unsigned short* Vt  = (unsigned short*)(ws + 20971520);      // 2 MB [b][h][dh][n]
    unsigned short* Xg  = (unsigned short*)(ws + 23068672);      // 2 MB
    unsigned short* Og  = (unsigned short*)(ws + 25165824);      // 2 MB
    unsigned short* Wt  = (unsigned short*)(ws + 27262976);      // 3 MB [4*1024][384]
    unsigned short* Wot = (unsigned short*)(ws + 30408704);      // 0.75 MB [384][1024]

    k_transpose_all<<<dim3(32, 32, 5), 256, 0, stream>>>(wq, wk, wv, wg, wo, Wt, Wot);
    k_bias<<<4096, 256, 0, stream>>>(pw, gamma, beta, wb, abb, SP);
    k_proj<<<dim3(8, 32), 256, 0, stream>>>(single, Wt, Qb, Kb, Vt, Xg);
    k_flash<<<dim3(8, 32), 256, 0, stream>>>(Qb, Kb, Vt, SP, Xg, Og);
    k_out<<<dim3(8, 3), 256, 0, stream>>>(Og, Wot, out);
}

// Round 6
// 135.877 us; speedup vs baseline: 1.2120x; 1.2120x over previous
//
#include <hip/hip_runtime.h>
#include <hip/hip_bf16.h>

#define B_ 2
#define N_ 512
#define DS_ 384
#define DP_ 128
#define H_ 16
#define DH_ 64
#define DI_ 1024
#define MAXSEQ 2048
#define PAD 8

typedef float f32x4 __attribute__((ext_vector_type(4)));
typedef short bf16x8 __attribute__((ext_vector_type(8)));

__device__ __forceinline__ unsigned short f2b(float f) {
    unsigned int u = __builtin_bit_cast(unsigned int, f);
    u += 0x7FFFu + ((u >> 16) & 1u);
    return (unsigned short)(u >> 16);
}
__device__ __forceinline__ float b2f(unsigned short s) {
    unsigned int u = ((unsigned int)s) << 16;
    return __builtin_bit_cast(float, u);
}

// -------- weight transposes + bias-GEMM prep (Gh = gamma*w, Ssum, Tsum) -----
__global__ __launch_bounds__(256) void k_transpose_all(const float* __restrict__ wq,
                                                       const float* __restrict__ wk,
                                                       const float* __restrict__ wv,
                                                       const float* __restrict__ wg,
                                                       const float* __restrict__ wo,
                                                       const float* __restrict__ gamma,
                                                       const float* __restrict__ beta,
                                                       const float* __restrict__ wb,
                                                       unsigned short* __restrict__ Wt,
                                                       unsigned short* __restrict__ Wot,
                                                       unsigned short* __restrict__ GhG,
                                                       float* __restrict__ SsG,
                                                       float* __restrict__ TsG) {
    int z = blockIdx.z;
    if (z == 5) {                       // prep for k_bias (one block only)
        if (blockIdx.x || blockIdx.y) return;
        int t = threadIdx.x;
        for (int idx = t; idx < DP_ * H_; idx += 256) {
            int d = idx >> 4, h = idx & 15;
            GhG[h * DP_ + d] = f2b(gamma[d] * wb[idx]);
        }
        if (t < 32) {
            int h = t & 15;
            const float* src = (t >= 16) ? beta : gamma;
            float s = 0.f;
            for (int d = 0; d < DP_; ++d) s = fmaf(src[d], wb[d * H_ + h], s);
            if (t >= 16) TsG[h] = s; else SsG[h] = s;
        }
        return;
    }
    __shared__ float tile[32][33];
    const float* in;
    unsigned short* out;
    int R, C;
    if (z < 4) {
        in = (z == 0) ? wq : (z == 1) ? wk : (z == 2) ? wv : wg;
        out = Wt + (long)z * 1024 * 384;
        R = 384; C = 1024;
    } else {
        in = wo; out = Wot; R = 1024; C = 384;
    }
    int c0 = blockIdx.x * 32, r0 = blockIdx.y * 32;
    if (c0 >= C || r0 >= R) return;
    int tx = threadIdx.x & 31, ty = threadIdx.x >> 5;
    #pragma unroll
    for (int i = ty; i < 32; i += 8)
        tile[i][tx] = in[(long)(r0 + i) * C + (c0 + tx)];
    __syncthreads();
    #pragma unroll
    for (int i = ty; i < 32; i += 8)
        out[(long)(c0 + i) * R + (r0 + tx)] = f2b(tile[tx][i]);
}

// ---------------- bias: LN(pairwise) @ w_bias + abb -> bf16 [b][h][i][j] ----
// v4: pure-register — fragments loaded straight from global fp32, converted
// in-reg, MFMA vs global Gh table. No block-wide LDS staging, no syncthreads.
__global__ __launch_bounds__(256) void k_bias(const float* __restrict__ pw,
                                              const float* __restrict__ abb,
                                              const unsigned short* __restrict__ GhG,
                                              const float* __restrict__ SsG,
                                              const float* __restrict__ TsG,
                                              unsigned short* __restrict__ biasP) {
    __shared__ float rsum[4][2][16] __attribute__((aligned(16)));
    __shared__ float rsq[4][2][16] __attribute__((aligned(16)));
    int t = threadIdx.x;
    int w = t >> 6, lane = t & 63;
    int lane15 = lane & 15, kg = lane >> 4;
    long p0 = (long)blockIdx.x * 128;           // first (b,i,j)-flat row
    int i_blk = (int)((p0 >> 9) & (N_ - 1));
    int j0 = (int)(p0 & (N_ - 1));
    long bb = p0 >> 18;

    // B fragments (heads) from global (4 KB, L2-hot)
    bf16x8 gb[4];
    #pragma unroll
    for (int kk = 0; kk < 4; ++kk)
        gb[kk] = *(const bf16x8*)&GhG[lane15 * DP_ + kk * 32 + kg * 8];
    float sh = SsG[lane15], th = TsG[lane15];
    unsigned short* planeBase = biasP + ((bb * H_ + lane15) * N_ + i_blk) * N_ + j0;

    #pragma unroll
    for (int m = 0; m < 2; ++m) {
        int rbase = w * 32 + m * 16;            // 16 j-rows owned this iter
        const float* rowp = pw + ((p0 + rbase + lane15) << 7) + kg * 8;
        float4 xa[4], xb4[4];
        #pragma unroll
        for (int kk = 0; kk < 4; ++kk) {
            xa[kk]  = *(const float4*)(rowp + kk * 32);
            xb4[kk] = *(const float4*)(rowp + kk * 32 + 4);
        }
        // local stats over this lane's 32 elems (exact fp32)
        float s = 0.f, q = 0.f;
        #pragma unroll
        for (int kk = 0; kk < 4; ++kk) {
            s += xa[kk].x + xa[kk].y + xa[kk].z + xa[kk].w;
            s += xb4[kk].x + xb4[kk].y + xb4[kk].z + xb4[kk].w;
            q = fmaf(xa[kk].x, xa[kk].x, q); q = fmaf(xa[kk].y, xa[kk].y, q);
            q = fmaf(xa[kk].z, xa[kk].z, q); q = fmaf(xa[kk].w, xa[kk].w, q);
            q = fmaf(xb4[kk].x, xb4[kk].x, q); q = fmaf(xb4[kk].y, xb4[kk].y, q);
            q = fmaf(xb4[kk].z, xb4[kk].z, q); q = fmaf(xb4[kk].w, xb4[kk].w, q);
        }
        // combine the 4 sibling lanes (same row) — only 4 shuffles
        s += __shfl_xor(s, 16); s += __shfl_xor(s, 32);
        q += __shfl_xor(q, 16); q += __shfl_xor(q, 32);
        if (lane < 16) { rsum[w][m][lane15] = s; rsq[w][m][lane15] = q; }

        // convert fragments and MFMA
        f32x4 acc = {};
        #pragma unroll
        for (int kk = 0; kk < 4; ++kk) {
            bf16x8 a;
            unsigned short* ap = (unsigned short*)&a;
            ap[0] = f2b(xa[kk].x);  ap[1] = f2b(xa[kk].y);
            ap[2] = f2b(xa[kk].z);  ap[3] = f2b(xa[kk].w);
            ap[4] = f2b(xb4[kk].x); ap[5] = f2b(xb4[kk].y);
            ap[6] = f2b(xb4[kk].z); ap[7] = f2b(xb4[kk].w);
            acc = __builtin_amdgcn_mfma_f32_16x16x32_bf16(a, gb[kk], acc, 0, 0, 0);
        }
        // epilogue: lane holds col h=lane15, rows rbase + kg*4 + r
        int jr = rbase + kg * 4;
        float4 rs = *(const float4*)&rsum[w][m][kg * 4];
        float4 rq = *(const float4*)&rsq[w][m][kg * 4];
        float4 av = *(const float4*)(abb + (long)i_blk * MAXSEQ + j0 + jr);
        ushort4 res;
        float mu, var;
        mu = rs.x * (1.f / DP_); var = fmaf(rq.x, 1.f / DP_, -mu * mu);
        res.x = f2b(fmaf(rsqrtf(var + 1e-5f), acc[0] - mu * sh, th + av.x));
        mu = rs.y * (1.f / DP_); var = fmaf(rq.y, 1.f / DP_, -mu * mu);
        res.y = f2b(fmaf(rsqrtf(var + 1e-5f), acc[1] - mu * sh, th + av.y));
        mu = rs.z * (1.f / DP_); var = fmaf(rq.z, 1.f / DP_, -mu * mu);
        res.z = f2b(fmaf(rsqrtf(var + 1e-5f), acc[2] - mu * sh, th + av.z));
        mu = rs.w * (1.f / DP_); var = fmaf(rq.w, 1.f / DP_, -mu * mu);
        res.w = f2b(fmaf(rsqrtf(var + 1e-5f), acc[3] - mu * sh, th + av.w));
        *(ushort4*)(planeBase + jr) = res;
    }
}

// ---------------- QKVG projection GEMM (M=1024, N=4096, K=384) --------------
// Q is pre-scaled by 0.125 (folded attention scale).
__global__ __launch_bounds__(256) void k_proj(const float* __restrict__ X,
                                              const unsigned short* __restrict__ Wt,
                                              unsigned short* __restrict__ Qb,
                                              unsigned short* __restrict__ Kb,
                                              unsigned short* __restrict__ Vt,
                                              unsigned short* __restrict__ Xg) {
    __shared__ unsigned short As[128][64 + PAD];
    __shared__ unsigned short Bs[128][64 + PAD];
    int m0 = blockIdx.x * 128;
    int n0 = blockIdx.y * 128;
    int t = threadIdx.x;
    int wave = t >> 6, lane = t & 63;
    int wr = wave >> 1, wc = wave & 1;
    int lane15 = lane & 15, kg = lane >> 4;
    f32x4 acc[4][4] = {};
    for (int k0 = 0; k0 < DS_; k0 += 64) {
        __syncthreads();
        {
            int r = t >> 1, half = t & 1;
            const float4* src = (const float4*)(X + (long)(m0 + r) * DS_ + k0 + half * 32);
            unsigned short* dst = &As[r][half * 32];
            #pragma unroll
            for (int ii = 0; ii < 8; ++ii) {
                float4 v = src[ii];
                dst[ii * 4 + 0] = f2b(v.x); dst[ii * 4 + 1] = f2b(v.y);
                dst[ii * 4 + 2] = f2b(v.z); dst[ii * 4 + 3] = f2b(v.w);
            }
            const uint4* wsrc = (const uint4*)(Wt + (long)(n0 + r) * DS_ + k0 + half * 32);
            uint4* wdst = (uint4*)&Bs[r][half * 32];
            wdst[0] = wsrc[0]; wdst[1] = wsrc[1]; wdst[2] = wsrc[2]; wdst[3] = wsrc[3];
        }
        __syncthreads();
        #pragma unroll
        for (int ks = 0; ks < 2; ++ks) {
            bf16x8 a[4], bb[4];
            #pragma unroll
            for (int mf = 0; mf < 4; ++mf)
                a[mf] = *(const bf16x8*)&As[wr * 64 + mf * 16 + lane15][ks * 32 + kg * 8];
            #pragma unroll
            for (int nf = 0; nf < 4; ++nf)
                bb[nf] = *(const bf16x8*)&Bs[wc * 64 + nf * 16 + lane15][ks * 32 + kg * 8];
            #pragma unroll
            for (int mf = 0; mf < 4; ++mf)
                #pragma unroll
                for (int nf = 0; nf < 4; ++nf)
                    acc[mf][nf] = __builtin_amdgcn_mfma_f32_16x16x32_bf16(a[mf], bb[nf], acc[mf][nf], 0, 0, 0);
        }
    }
    int p = n0 >> 10;                 // which projection (q,k,v,g)
    int lgrp = lane >> 4;
    #pragma unroll
    for (int mf = 0; mf < 4; ++mf) {
        #pragma unroll
        for (int nf = 0; nf < 4; ++nf) {
            int col = n0 + wc * 64 + nf * 16 + lane15;
            int ch = col & 1023;
            int h = ch >> 6, dh = ch & 63;
            int row0 = m0 + wr * 64 + mf * 16 + lgrp * 4;
            if (p == 0 || p == 1) {
                unsigned short* base = (p == 0) ? Qb : Kb;
                float scl = (p == 0) ? 0.125f : 1.0f;
                #pragma unroll
                for (int r = 0; r < 4; ++r) {
                    int row = row0 + r;
                    int b = row >> 9, n = row & 511;
                    base[(((long)(b * 16 + h)) * 512 + n) * 64 + dh] = f2b(acc[mf][nf][r] * scl);
                }
            } else if (p == 2) {
                int b = row0 >> 9, n = row0 & 511;
                ushort4 v;
                v.x = f2b(acc[mf][nf][0]); v.y = f2b(acc[mf][nf][1]);
                v.z = f2b(acc[mf][nf][2]); v.w = f2b(acc[mf][nf][3]);
                *(ushort4*)&Vt[(((long)(b * 16 + h)) * 64 + dh) * 512 + n] = v;
            } else {
                #pragma unroll
                for (int r = 0; r < 4; ++r) {
                    int row = row0 + r;
                    Xg[(long)row * 1024 + ch] = f2b(acc[mf][nf][r]);
                }
            }
        }
    }
}

// ---------------- fused flash attention: S=Q@K^T+bias, softmax, P@V, gate ---
// grid (8 i-blocks, 32 bh), 256 threads (4 waves, wave w owns i-rows w*16..+16)
__global__ __launch_bounds__(256) void k_flash(const unsigned short* __restrict__ Qb,
                                               const unsigned short* __restrict__ Kb,
                                               const unsigned short* __restrict__ Vt,
                                               const unsigned short* __restrict__ biasP,
                                               const unsigned short* __restrict__ Xg,
                                               unsigned short* __restrict__ Og) {
    __shared__ unsigned short Kt[64][72];    // [j][dh]
    __shared__ unsigned short Vs[64][72];    // [dh][j]
    __shared__ unsigned short Bt[64][72];    // [i][j] bias tile
    __shared__ unsigned short Ps[4][16][72]; // per-wave P [i][j]
    int bh = blockIdx.y;
    int b = bh >> 4, h = bh & 15;
    int i0 = blockIdx.x * 64;
    int t = threadIdx.x, w = t >> 6, lane = t & 63;
    int lane15 = lane & 15, lgrp = lane >> 4;

    // Q fragments (B-operand), row i = i0 + w*16 + lane15, pre-scaled by 0.125
    bf16x8 qf[2];
    #pragma unroll
    for (int kk = 0; kk < 2; ++kk)
        qf[kk] = *(const bf16x8*)&Qb[((long)bh * 512 + i0 + w * 16 + lane15) * 64 + kk * 32 + lgrp * 8];

    float m_run = -1e30f, l_run = 0.f;
    f32x4 o[4] = {};   // o[nf][r] = O[i0+w*16+lgrp*4+r][nf*16+lane15]

    for (int jt = 0; jt < 8; ++jt) {
        int j0 = jt * 64;
        __syncthreads();   // previous tile fully consumed
        #pragma unroll
        for (int i = 0; i < 2; ++i) {
            int f = i * 256 + t;
            int r = f >> 3, c = f & 7;
            *(uint4*)&Kt[r][c * 8] = *(const uint4*)&Kb[((long)bh * 512 + j0 + r) * 64 + c * 8];
            *(uint4*)&Vs[r][c * 8] = *(const uint4*)&Vt[((long)bh * 64 + r) * 512 + j0 + c * 8];
            *(uint4*)&Bt[r][c * 8] = *(const uint4*)&biasP[(((long)bh * 512) + i0 + r) * 512 + j0 + c * 8];
        }
        __syncthreads();

        // S^T[j][i]: A = K[j][dh], B = Q[i][dh]  ->  lane holds col i=lane15, rows j
        f32x4 s[4];
        #pragma unroll
        for (int nf = 0; nf < 4; ++nf) {
            f32x4 z = {};
            #pragma unroll
            for (int kk = 0; kk < 2; ++kk) {
                bf16x8 af = *(const bf16x8*)&Kt[nf * 16 + lane15][kk * 32 + lgrp * 8];
                z = __builtin_amdgcn_mfma_f32_16x16x32_bf16(af, qf[kk], z, 0, 0, 0);
            }
            s[nf] = z;
        }
        // add bias: s[nf][r] is S[i = i0 + w*16 + lane15][j = j0 + nf*16 + lgrp*4 + r]
        #pragma unroll
        for (int nf = 0; nf < 4; ++nf)
            #pragma unroll
            for (int r = 0; r < 4; ++r)
                s[nf][r] += b2f(Bt[w * 16 + lane15][nf * 16 + lgrp * 4 + r]);

        // online softmax, lane owns row i (16 j-values per lane); reduce across
        // the 4 lanes sharing lane15 (xor 16, 32)
        float pmax = s[0][0];
        #pragma unroll
        for (int nf = 0; nf < 4; ++nf)
            #pragma unroll
            for (int r = 0; r < 4; ++r) pmax = fmaxf(pmax, s[nf][r]);
        pmax = fmaxf(pmax, __shfl_xor(pmax, 16));
        pmax = fmaxf(pmax, __shfl_xor(pmax, 32));
        float m_new = fmaxf(m_run, pmax);
        float scale = __expf(m_run - m_new);
        float psum = 0.f;
        #pragma unroll
        for (int nf = 0; nf < 4; ++nf)
            #pragma unroll
            for (int r = 0; r < 4; ++r) {
                s[nf][r] = __expf(s[nf][r] - m_new);
                psum += s[nf][r];
            }
        psum += __shfl_xor(psum, 16);
        psum += __shfl_xor(psum, 32);
        l_run = l_run * scale + psum;
        m_run = m_new;
        // rescale O (o's rows are i = lgrp*4 + r; fetch that row's scale)
        #pragma unroll
        for (int r = 0; r < 4; ++r) {
            float sc = __shfl(scale, lgrp * 4 + r);
            #pragma unroll
            for (int nf = 0; nf < 4; ++nf) o[nf][r] *= sc;
        }
        // P -> LDS (bf16), wave-private
        #pragma unroll
        for (int nf = 0; nf < 4; ++nf)
            #pragma unroll
            for (int r = 0; r < 4; ++r)
                Ps[w][lane15][nf * 16 + lgrp * 4 + r] = f2b(s[nf][r]);
        // PV: A = P[i][j] (row=lane15), B = V[dh][j] (row=lane15 of Vs)
        #pragma unroll
        for (int kk = 0; kk < 2; ++kk) {
            bf16x8 pa = *(const bf16x8*)&Ps[w][lane15][kk * 32 + lgrp * 8];
            #pragma unroll
            for (int nf = 0; nf < 4; ++nf) {
                bf16x8 vb = *(const bf16x8*)&Vs[nf * 16 + lane15][kk * 32 + lgrp * 8];
                o[nf] = __builtin_amdgcn_mfma_f32_16x16x32_bf16(pa, vb, o[nf], 0, 0, 0);
            }
        }
    }
    // epilogue: divide by l, sigmoid gate, store
    #pragma unroll
    for (int r = 0; r < 4; ++r) {
        float l_r = __shfl(l_run, lgrp * 4 + r);
        float inv = 1.f / l_r;
        long grow = (long)b * 512 + i0 + w * 16 + lgrp * 4 + r;
        #pragma unroll
        for (int nf = 0; nf < 4; ++nf) {
            int dh = nf * 16 + lane15;
            float xgv = b2f(Xg[grow * 1024 + h * 64 + dh]);
            float gate = 1.f / (1.f + __expf(-xgv));
            Og[grow * 1024 + h * 64 + dh] = f2b(o[nf][r] * inv * gate);
        }
    }
}

// ---------------- output GEMM: out = Og @ w_o (M=1024,N=384,K=1024) ---------
__global__ __launch_bounds__(256) void k_out(const unsigned short* __restrict__ Og,
                                             const unsigned short* __restrict__ Wot,
                                             float* __restrict__ out) {
    __shared__ unsigned short As[128][64 + PAD];
    __shared__ unsigned short Bs[128][64 + PAD];
    int m0 = blockIdx.x * 128, n0 = blockIdx.y * 128;
    int t = threadIdx.x, wave = t >> 6, lane = t & 63;
    int wr = wave >> 1, wc = wave & 1;
    int lane15 = lane & 15, kg = lane >> 4;
    f32x4 acc[4][4] = {};
    for (int k0 = 0; k0 < 1024; k0 += 64) {
        __syncthreads();
        {
            int r = t >> 1, half = t & 1;
            const uint4* src = (const uint4*)(Og + (long)(m0 + r) * 1024 + k0 + half * 32);
            uint4* dst = (uint4*)&As[r][half * 32];
            dst[0] = src[0]; dst[1] = src[1]; dst[2] = src[2]; dst[3] = src[3];
            const uint4* wsrc = (const uint4*)(Wot + (long)(n0 + r) * 1024 + k0 + half * 32);
            uint4* wdst = (uint4*)&Bs[r][half * 32];
            wdst[0] = wsrc[0]; wdst[1] = wsrc[1]; wdst[2] = wsrc[2]; wdst[3] = wsrc[3];
        }
        __syncthreads();
        #pragma unroll
        for (int ks = 0; ks < 2; ++ks) {
            bf16x8 a[4], bb[4];
            #pragma unroll
            for (int mf = 0; mf < 4; ++mf)
                a[mf] = *(const bf16x8*)&As[wr * 64 + mf * 16 + lane15][ks * 32 + kg * 8];
            #pragma unroll
            for (int nf = 0; nf < 4; ++nf)
                bb[nf] = *(const bf16x8*)&Bs[wc * 64 + nf * 16 + lane15][ks * 32 + kg * 8];
            #pragma unroll
            for (int mf = 0; mf < 4; ++mf)
                #pragma unroll
                for (int nf = 0; nf < 4; ++nf)
                    acc[mf][nf] = __builtin_amdgcn_mfma_f32_16x16x32_bf16(a[mf], bb[nf], acc[mf][nf], 0, 0, 0);
        }
    }
    int lgrp = lane >> 4;
    #pragma unroll
    for (int mf = 0; mf < 4; ++mf) {
        #pragma unroll
        for (int nf = 0; nf < 4; ++nf) {
            int col = n0 + wc * 64 + nf * 16 + lane15;
            int row0 = m0 + wr * 64 + mf * 16 + lgrp * 4;
            #pragma unroll
            for (int r = 0; r < 4; ++r)
                out[(long)(row0 + r) * DS_ + col] = acc[mf][nf][r];
        }
    }
}

extern "C" void kernel_launch(void* const* d_in, const int* in_sizes, int n_in,
                              void* d_out, int out_size, void* d_ws, size_t ws_size,
                              hipStream_t stream) {
    const float* single = (const float*)d_in[0];
    const float* pw     = (const float*)d_in[1];
    const float* gamma  = (const float*)d_in[2];
    const float* beta   = (const float*)d_in[3];
    const float* wb     = (const float*)d_in[4];
    const float* abb    = (const float*)d_in[5];
    const float* wq     = (const float*)d_in[6];
    const float* wk     = (const float*)d_in[7];
    const float* wv     = (const float*)d_in[8];
    const float* wg     = (const float*)d_in[9];
    const float* wo     = (const float*)d_in[10];
    float* out = (float*)d_out;
    char* ws = (char*)d_ws;

    unsigned short* SP  = (unsigned short*)(ws);                 // 16 MB bias [b][h][i][j]
    unsigned short* Qb  = (unsigned short*)(ws + 16777216);      // 2 MB (pre-scaled 0.125)
    unsigned short* Kb  = (unsigned short*)(ws + 18874368);      // 2 MB
    unsigned short* Vt  = (unsigned short*)(ws + 20971520);      // 2 MB [b][h][dh][n]
    unsigned short* Xg  = (unsigned short*)(ws + 23068672);      // 2 MB
    unsigned short* Og  = (unsigned short*)(ws + 25165824);      // 2 MB
    unsigned short* Wt  = (unsigned short*)(ws + 27262976);      // 3 MB [4*1024][384]
    unsigned short* Wot = (unsigned short*)(ws + 30408704);      // 0.75 MB [384][1024]
    unsigned short* GhG = (unsigned short*)(ws + 31195136);      // 4 KB  [16][128] bf16
    float* SsG          = (float*)(ws + 31199232);               // 64 B
    float* TsG          = (float*)(ws + 31199296);               // 64 B

    k_transpose_all<<<dim3(32, 32, 6), 256, 0, stream>>>(wq, wk, wv, wg, wo,
                                                         gamma, beta, wb,
                                                         Wt, Wot, GhG, SsG, TsG);
    k_bias<<<4096, 256, 0, stream>>>(pw, abb, GhG, SsG, TsG, SP);
    k_proj<<<dim3(8, 32), 256, 0, stream>>>(single, Wt, Qb, Kb, Vt, Xg);
    k_flash<<<dim3(8, 32), 256, 0, stream>>>(Qb, Kb, Vt, SP, Xg, Og);
    k_out<<<dim3(8, 3), 256, 0, stream>>>(Og, Wot, out);
}

// Round 7
// 132.807 us; speedup vs baseline: 1.2400x; 1.0231x over previous
//
#include <hip/hip_runtime.h>
#include <hip/hip_bf16.h>

#define B_ 2
#define N_ 512
#define DS_ 384
#define DP_ 128
#define H_ 16
#define DH_ 64
#define DI_ 1024
#define MAXSEQ 2048
#define PAD 8

typedef float f32x4 __attribute__((ext_vector_type(4)));
typedef short bf16x8 __attribute__((ext_vector_type(8)));

__device__ __forceinline__ unsigned short f2b(float f) {
    unsigned int u = __builtin_bit_cast(unsigned int, f);
    u += 0x7FFFu + ((u >> 16) & 1u);
    return (unsigned short)(u >> 16);
}
__device__ __forceinline__ float b2f(unsigned short s) {
    unsigned int u = ((unsigned int)s) << 16;
    return __builtin_bit_cast(float, u);
}

// -------- weight transposes + bias-GEMM prep (Gh = gamma*w, Ssum, Tsum) -----
__global__ __launch_bounds__(256) void k_transpose_all(const float* __restrict__ wq,
                                                       const float* __restrict__ wk,
                                                       const float* __restrict__ wv,
                                                       const float* __restrict__ wg,
                                                       const float* __restrict__ wo,
                                                       const float* __restrict__ gamma,
                                                       const float* __restrict__ beta,
                                                       const float* __restrict__ wb,
                                                       unsigned short* __restrict__ Wt,
                                                       unsigned short* __restrict__ Wot,
                                                       unsigned short* __restrict__ GhG,
                                                       float* __restrict__ SsG,
                                                       float* __restrict__ TsG) {
    int z = blockIdx.z;
    if (z == 5) {                       // prep for k_bias (one block only)
        if (blockIdx.x || blockIdx.y) return;
        int t = threadIdx.x;
        for (int idx = t; idx < DP_ * H_; idx += 256) {
            int d = idx >> 4, h = idx & 15;
            GhG[h * DP_ + d] = f2b(gamma[d] * wb[idx]);
        }
        if (t < 32) {
            int h = t & 15;
            const float* src = (t >= 16) ? beta : gamma;
            float s = 0.f;
            for (int d = 0; d < DP_; ++d) s = fmaf(src[d], wb[d * H_ + h], s);
            if (t >= 16) TsG[h] = s; else SsG[h] = s;
        }
        return;
    }
    __shared__ float tile[32][33];
    const float* in;
    unsigned short* out;
    int R, C;
    if (z < 4) {
        in = (z == 0) ? wq : (z == 1) ? wk : (z == 2) ? wv : wg;
        out = Wt + (long)z * 1024 * 384;
        R = 384; C = 1024;
    } else {
        in = wo; out = Wot; R = 1024; C = 384;
    }
    int c0 = blockIdx.x * 32, r0 = blockIdx.y * 32;
    if (c0 >= C || r0 >= R) return;
    int tx = threadIdx.x & 31, ty = threadIdx.x >> 5;
    #pragma unroll
    for (int i = ty; i < 32; i += 8)
        tile[i][tx] = in[(long)(r0 + i) * C + (c0 + tx)];
    __syncthreads();
    #pragma unroll
    for (int i = ty; i < 32; i += 8)
        out[(long)(c0 + i) * R + (r0 + tx)] = f2b(tile[tx][i]);
}

// ---------------- bias: LN(pairwise) @ w_bias + abb -> bf16 [b][h][i][j] ----
// v5: contiguous wave reads -> LDS (XOR-swizzled write), swizzled ds_read_b128
// fragments, register stats, MFMA dot. Block = 64 rows, grid 8192.
__global__ __launch_bounds__(256) void k_bias(const float* __restrict__ pw,
                                              const float* __restrict__ abb,
                                              const unsigned short* __restrict__ GhG,
                                              const float* __restrict__ SsG,
                                              const float* __restrict__ TsG,
                                              unsigned short* __restrict__ biasP) {
    __shared__ float Xs[64 * 128];                          // 32 KB, swizzled rows
    __shared__ float rsum[4][16] __attribute__((aligned(16)));
    __shared__ float rsq[4][16] __attribute__((aligned(16)));
    int t = threadIdx.x;
    int w = t >> 6, lane = t & 63;
    int lane15 = lane & 15, kg = lane >> 4;
    long p0 = (long)blockIdx.x * 64;            // first (b,i,j)-flat row
    int i_blk = (int)((p0 >> 9) & (N_ - 1));
    int j0 = (int)(p0 & (N_ - 1));
    long bb = p0 >> 18;

    // stage: linear 1KB-per-wave-instr global reads, XOR-swizzled LDS writes
    const char* src = (const char*)(pw + (p0 << 7));
    char* lds = (char*)Xs;
    #pragma unroll
    for (int c = 0; c < 8; ++c) {
        int L = c * 4096 + t * 16;
        int row = L >> 9, b = L & 511;
        uint4 v = *(const uint4*)(src + L);
        *(uint4*)(lds + (row << 9) + (b ^ ((row & 7) << 4))) = v;
    }

    // B fragments (heads) from global (4 KB, L2-hot)
    bf16x8 gb[4];
    #pragma unroll
    for (int kk = 0; kk < 4; ++kk)
        gb[kk] = *(const bf16x8*)&GhG[lane15 * DP_ + kk * 32 + kg * 8];
    float sh = SsG[lane15], th = TsG[lane15];
    __syncthreads();

    // fragments: row = w*16 + lane15, k-chunk kk, floats kg*8..+8 (swizzled read)
    int row = w * 16 + lane15;
    const char* rbase = lds + (row << 9);
    int sw = (lane15 & 7) << 4;
    f32x4 xa[4], xb4[4];
    #pragma unroll
    for (int kk = 0; kk < 4; ++kk) {
        int b0 = kk * 128 + kg * 32;
        xa[kk]  = *(const f32x4*)(rbase + ((b0) ^ sw));
        xb4[kk] = *(const f32x4*)(rbase + ((b0 + 16) ^ sw));
    }
    // local stats over this lane's 32 elems (exact fp32)
    float s = 0.f, q = 0.f;
    #pragma unroll
    for (int kk = 0; kk < 4; ++kk) {
        s += xa[kk][0] + xa[kk][1] + xa[kk][2] + xa[kk][3];
        s += xb4[kk][0] + xb4[kk][1] + xb4[kk][2] + xb4[kk][3];
        #pragma unroll
        for (int e = 0; e < 4; ++e) {
            q = fmaf(xa[kk][e], xa[kk][e], q);
            q = fmaf(xb4[kk][e], xb4[kk][e], q);
        }
    }
    // combine the 4 sibling lanes (same row)
    s += __shfl_xor(s, 16); s += __shfl_xor(s, 32);
    q += __shfl_xor(q, 16); q += __shfl_xor(q, 32);
    if (lane < 16) { rsum[w][lane15] = s; rsq[w][lane15] = q; }

    // convert fragments and MFMA
    f32x4 acc = {};
    #pragma unroll
    for (int kk = 0; kk < 4; ++kk) {
        bf16x8 a;
        unsigned short* ap = (unsigned short*)&a;
        ap[0] = f2b(xa[kk][0]);  ap[1] = f2b(xa[kk][1]);
        ap[2] = f2b(xa[kk][2]);  ap[3] = f2b(xa[kk][3]);
        ap[4] = f2b(xb4[kk][0]); ap[5] = f2b(xb4[kk][1]);
        ap[6] = f2b(xb4[kk][2]); ap[7] = f2b(xb4[kk][3]);
        acc = __builtin_amdgcn_mfma_f32_16x16x32_bf16(a, gb[kk], acc, 0, 0, 0);
    }
    // epilogue: lane holds col h=lane15, rows w*16 + kg*4 + r
    int jr = w * 16 + kg * 4;
    float4 rs = *(const float4*)&rsum[w][kg * 4];
    float4 rq = *(const float4*)&rsq[w][kg * 4];
    float4 av = *(const float4*)(abb + (long)i_blk * MAXSEQ + j0 + jr);
    unsigned short* planeBase = biasP + ((bb * H_ + lane15) * N_ + i_blk) * N_ + j0;
    ushort4 res;
    float mu, var;
    mu = rs.x * (1.f / DP_); var = fmaf(rq.x, 1.f / DP_, -mu * mu);
    res.x = f2b(fmaf(rsqrtf(var + 1e-5f), acc[0] - mu * sh, th + av.x));
    mu = rs.y * (1.f / DP_); var = fmaf(rq.y, 1.f / DP_, -mu * mu);
    res.y = f2b(fmaf(rsqrtf(var + 1e-5f), acc[1] - mu * sh, th + av.y));
    mu = rs.z * (1.f / DP_); var = fmaf(rq.z, 1.f / DP_, -mu * mu);
    res.z = f2b(fmaf(rsqrtf(var + 1e-5f), acc[2] - mu * sh, th + av.z));
    mu = rs.w * (1.f / DP_); var = fmaf(rq.w, 1.f / DP_, -mu * mu);
    res.w = f2b(fmaf(rsqrtf(var + 1e-5f), acc[3] - mu * sh, th + av.w));
    *(ushort4*)(planeBase + jr) = res;
}

// ---------------- QKVG projection GEMM (M=1024, N=4096, K=384) --------------
// Q is pre-scaled by 0.125 (folded attention scale).
__global__ __launch_bounds__(256) void k_proj(const float* __restrict__ X,
                                              const unsigned short* __restrict__ Wt,
                                              unsigned short* __restrict__ Qb,
                                              unsigned short* __restrict__ Kb,
                                              unsigned short* __restrict__ Vt,
                                              unsigned short* __restrict__ Xg) {
    __shared__ unsigned short As[128][64 + PAD];
    __shared__ unsigned short Bs[128][64 + PAD];
    int m0 = blockIdx.x * 128;
    int n0 = blockIdx.y * 128;
    int t = threadIdx.x;
    int wave = t >> 6, lane = t & 63;
    int wr = wave >> 1, wc = wave & 1;
    int lane15 = lane & 15, kg = lane >> 4;
    f32x4 acc[4][4] = {};
    for (int k0 = 0; k0 < DS_; k0 += 64) {
        __syncthreads();
        {
            int r = t >> 1, half = t & 1;
            const float4* src = (const float4*)(X + (long)(m0 + r) * DS_ + k0 + half * 32);
            unsigned short* dst = &As[r][half * 32];
            #pragma unroll
            for (int ii = 0; ii < 8; ++ii) {
                float4 v = src[ii];
                dst[ii * 4 + 0] = f2b(v.x); dst[ii * 4 + 1] = f2b(v.y);
                dst[ii * 4 + 2] = f2b(v.z); dst[ii * 4 + 3] = f2b(v.w);
            }
            const uint4* wsrc = (const uint4*)(Wt + (long)(n0 + r) * DS_ + k0 + half * 32);
            uint4* wdst = (uint4*)&Bs[r][half * 32];
            wdst[0] = wsrc[0]; wdst[1] = wsrc[1]; wdst[2] = wsrc[2]; wdst[3] = wsrc[3];
        }
        __syncthreads();
        #pragma unroll
        for (int ks = 0; ks < 2; ++ks) {
            bf16x8 a[4], bb[4];
            #pragma unroll
            for (int mf = 0; mf < 4; ++mf)
                a[mf] = *(const bf16x8*)&As[wr * 64 + mf * 16 + lane15][ks * 32 + kg * 8];
            #pragma unroll
            for (int nf = 0; nf < 4; ++nf)
                bb[nf] = *(const bf16x8*)&Bs[wc * 64 + nf * 16 + lane15][ks * 32 + kg * 8];
            #pragma unroll
            for (int mf = 0; mf < 4; ++mf)
                #pragma unroll
                for (int nf = 0; nf < 4; ++nf)
                    acc[mf][nf] = __builtin_amdgcn_mfma_f32_16x16x32_bf16(a[mf], bb[nf], acc[mf][nf], 0, 0, 0);
        }
    }
    int p = n0 >> 10;                 // which projection (q,k,v,g)
    int lgrp = lane >> 4;
    #pragma unroll
    for (int mf = 0; mf < 4; ++mf) {
        #pragma unroll
        for (int nf = 0; nf < 4; ++nf) {
            int col = n0 + wc * 64 + nf * 16 + lane15;
            int ch = col & 1023;
            int h = ch >> 6, dh = ch & 63;
            int row0 = m0 + wr * 64 + mf * 16 + lgrp * 4;
            if (p == 0 || p == 1) {
                unsigned short* base = (p == 0) ? Qb : Kb;
                float scl = (p == 0) ? 0.125f : 1.0f;
                #pragma unroll
                for (int r = 0; r < 4; ++r) {
                    int row = row0 + r;
                    int b = row >> 9, n = row & 511;
                    base[(((long)(b * 16 + h)) * 512 + n) * 64 + dh] = f2b(acc[mf][nf][r] * scl);
                }
            } else if (p == 2) {
                int b = row0 >> 9, n = row0 & 511;
                ushort4 v;
                v.x = f2b(acc[mf][nf][0]); v.y = f2b(acc[mf][nf][1]);
                v.z = f2b(acc[mf][nf][2]); v.w = f2b(acc[mf][nf][3]);
                *(ushort4*)&Vt[(((long)(b * 16 + h)) * 64 + dh) * 512 + n] = v;
            } else {
                #pragma unroll
                for (int r = 0; r < 4; ++r) {
                    int row = row0 + r;
                    Xg[(long)row * 1024 + ch] = f2b(acc[mf][nf][r]);
                }
            }
        }
    }
}

// ---------------- fused flash attention: S=Q@K^T+bias, softmax, P@V, gate ---
// grid (8 i-blocks, 32 bh), 256 threads (4 waves, wave w owns i-rows w*16..+16)
__global__ __launch_bounds__(256) void k_flash(const unsigned short* __restrict__ Qb,
                                               const unsigned short* __restrict__ Kb,
                                               const unsigned short* __restrict__ Vt,
                                               const unsigned short* __restrict__ biasP,
                                               const unsigned short* __restrict__ Xg,
                                               unsigned short* __restrict__ Og) {
    __shared__ unsigned short Kt[64][72];    // [j][dh]
    __shared__ unsigned short Vs[64][72];    // [dh][j]
    __shared__ unsigned short Bt[64][72];    // [i][j] bias tile
    __shared__ unsigned short Ps[4][16][72]; // per-wave P [i][j]
    int bh = blockIdx.y;
    int b = bh >> 4, h = bh & 15;
    int i0 = blockIdx.x * 64;
    int t = threadIdx.x, w = t >> 6, lane = t & 63;
    int lane15 = lane & 15, lgrp = lane >> 4;

    // Q fragments (B-operand), row i = i0 + w*16 + lane15, pre-scaled by 0.125
    bf16x8 qf[2];
    #pragma unroll
    for (int kk = 0; kk < 2; ++kk)
        qf[kk] = *(const bf16x8*)&Qb[((long)bh * 512 + i0 + w * 16 + lane15) * 64 + kk * 32 + lgrp * 8];

    float m_run = -1e30f, l_run = 0.f;
    f32x4 o[4] = {};   // o[nf][r] = O[i0+w*16+lgrp*4+r][nf*16+lane15]

    for (int jt = 0; jt < 8; ++jt) {
        int j0 = jt * 64;
        __syncthreads();   // previous tile fully consumed
        #pragma unroll
        for (int i = 0; i < 2; ++i) {
            int f = i * 256 + t;
            int r = f >> 3, c = f & 7;
            *(uint4*)&Kt[r][c * 8] = *(const uint4*)&Kb[((long)bh * 512 + j0 + r) * 64 + c * 8];
            *(uint4*)&Vs[r][c * 8] = *(const uint4*)&Vt[((long)bh * 64 + r) * 512 + j0 + c * 8];
            *(uint4*)&Bt[r][c * 8] = *(const uint4*)&biasP[(((long)bh * 512) + i0 + r) * 512 + j0 + c * 8];
        }
        __syncthreads();

        // S^T[j][i]: A = K[j][dh], B = Q[i][dh]  ->  lane holds col i=lane15, rows j
        f32x4 s[4];
        #pragma unroll
        for (int nf = 0; nf < 4; ++nf) {
            f32x4 z = {};
            #pragma unroll
            for (int kk = 0; kk < 2; ++kk) {
                bf16x8 af = *(const bf16x8*)&Kt[nf * 16 + lane15][kk * 32 + lgrp * 8];
                z = __builtin_amdgcn_mfma_f32_16x16x32_bf16(af, qf[kk], z, 0, 0, 0);
            }
            s[nf] = z;
        }
        // add bias: s[nf][r] is S[i = i0 + w*16 + lane15][j = j0 + nf*16 + lgrp*4 + r]
        #pragma unroll
        for (int nf = 0; nf < 4; ++nf)
            #pragma unroll
            for (int r = 0; r < 4; ++r)
                s[nf][r] += b2f(Bt[w * 16 + lane15][nf * 16 + lgrp * 4 + r]);

        // online softmax, lane owns row i (16 j-values per lane); reduce across
        // the 4 lanes sharing lane15 (xor 16, 32)
        float pmax = s[0][0];
        #pragma unroll
        for (int nf = 0; nf < 4; ++nf)
            #pragma unroll
            for (int r = 0; r < 4; ++r) pmax = fmaxf(pmax, s[nf][r]);
        pmax = fmaxf(pmax, __shfl_xor(pmax, 16));
        pmax = fmaxf(pmax, __shfl_xor(pmax, 32));
        float m_new = fmaxf(m_run, pmax);
        float scale = __expf(m_run - m_new);
        float psum = 0.f;
        #pragma unroll
        for (int nf = 0; nf < 4; ++nf)
            #pragma unroll
            for (int r = 0; r < 4; ++r) {
                s[nf][r] = __expf(s[nf][r] - m_new);
                psum += s[nf][r];
            }
        psum += __shfl_xor(psum, 16);
        psum += __shfl_xor(psum, 32);
        l_run = l_run * scale + psum;
        m_run = m_new;
        // rescale O (o's rows are i = lgrp*4 + r; fetch that row's scale)
        #pragma unroll
        for (int r = 0; r < 4; ++r) {
            float sc = __shfl(scale, lgrp * 4 + r);
            #pragma unroll
            for (int nf = 0; nf < 4; ++nf) o[nf][r] *= sc;
        }
        // P -> LDS (bf16), wave-private
        #pragma unroll
        for (int nf = 0; nf < 4; ++nf)
            #pragma unroll
            for (int r = 0; r < 4; ++r)
                Ps[w][lane15][nf * 16 + lgrp * 4 + r] = f2b(s[nf][r]);
        // PV: A = P[i][j] (row=lane15), B = V[dh][j] (row=lane15 of Vs)
        #pragma unroll
        for (int kk = 0; kk < 2; ++kk) {
            bf16x8 pa = *(const bf16x8*)&Ps[w][lane15][kk * 32 + lgrp * 8];
            #pragma unroll
            for (int nf = 0; nf < 4; ++nf) {
                bf16x8 vb = *(const bf16x8*)&Vs[nf * 16 + lane15][kk * 32 + lgrp * 8];
                o[nf] = __builtin_amdgcn_mfma_f32_16x16x32_bf16(pa, vb, o[nf], 0, 0, 0);
            }
        }
    }
    // epilogue: divide by l, sigmoid gate, store
    #pragma unroll
    for (int r = 0; r < 4; ++r) {
        float l_r = __shfl(l_run, lgrp * 4 + r);
        float inv = 1.f / l_r;
        long grow = (long)b * 512 + i0 + w * 16 + lgrp * 4 + r;
        #pragma unroll
        for (int nf = 0; nf < 4; ++nf) {
            int dh = nf * 16 + lane15;
            float xgv = b2f(Xg[grow * 1024 + h * 64 + dh]);
            float gate = 1.f / (1.f + __expf(-xgv));
            Og[grow * 1024 + h * 64 + dh] = f2b(o[nf][r] * inv * gate);
        }
    }
}

// ---------------- output GEMM: out = Og @ w_o (M=1024,N=384,K=1024) ---------
__global__ __launch_bounds__(256) void k_out(const unsigned short* __restrict__ Og,
                                             const unsigned short* __restrict__ Wot,
                                             float* __restrict__ out) {
    __shared__ unsigned short As[128][64 + PAD];
    __shared__ unsigned short Bs[128][64 + PAD];
    int m0 = blockIdx.x * 128, n0 = blockIdx.y * 128;
    int t = threadIdx.x, wave = t >> 6, lane = t & 63;
    int wr = wave >> 1, wc = wave & 1;
    int lane15 = lane & 15, kg = lane >> 4;
    f32x4 acc[4][4] = {};
    for (int k0 = 0; k0 < 1024; k0 += 64) {
        __syncthreads();
        {
            int r = t >> 1, half = t & 1;
            const uint4* src = (const uint4*)(Og + (long)(m0 + r) * 1024 + k0 + half * 32);
            uint4* dst = (uint4*)&As[r][half * 32];
            dst[0] = src[0]; dst[1] = src[1]; dst[2] = src[2]; dst[3] = src[3];
            const uint4* wsrc = (const uint4*)(Wot + (long)(n0 + r) * 1024 + k0 + half * 32);
            uint4* wdst = (uint4*)&Bs[r][half * 32];
            wdst[0] = wsrc[0]; wdst[1] = wsrc[1]; wdst[2] = wsrc[2]; wdst[3] = wsrc[3];
        }
        __syncthreads();
        #pragma unroll
        for (int ks = 0; ks < 2; ++ks) {
            bf16x8 a[4], bb[4];
            #pragma unroll
            for (int mf = 0; mf < 4; ++mf)
                a[mf] = *(const bf16x8*)&As[wr * 64 + mf * 16 + lane15][ks * 32 + kg * 8];
            #pragma unroll
            for (int nf = 0; nf < 4; ++nf)
                bb[nf] = *(const bf16x8*)&Bs[wc * 64 + nf * 16 + lane15][ks * 32 + kg * 8];
            #pragma unroll
            for (int mf = 0; mf < 4; ++mf)
                #pragma unroll
                for (int nf = 0; nf < 4; ++nf)
                    acc[mf][nf] = __builtin_amdgcn_mfma_f32_16x16x32_bf16(a[mf], bb[nf], acc[mf][nf], 0, 0, 0);
        }
    }
    int lgrp = lane >> 4;
    #pragma unroll
    for (int mf = 0; mf < 4; ++mf) {
        #pragma unroll
        for (int nf = 0; nf < 4; ++nf) {
            int col = n0 + wc * 64 + nf * 16 + lane15;
            int row0 = m0 + wr * 64 + mf * 16 + lgrp * 4;
            #pragma unroll
            for (int r = 0; r < 4; ++r)
                out[(long)(row0 + r) * DS_ + col] = acc[mf][nf][r];
        }
    }
}

extern "C" void kernel_launch(void* const* d_in, const int* in_sizes, int n_in,
                              void* d_out, int out_size, void* d_ws, size_t ws_size,
                              hipStream_t stream) {
    const float* single = (const float*)d_in[0];
    const float* pw     = (const float*)d_in[1];
    const float* gamma  = (const float*)d_in[2];
    const float* beta   = (const float*)d_in[3];
    const float* wb     = (const float*)d_in[4];
    const float* abb    = (const float*)d_in[5];
    const float* wq     = (const float*)d_in[6];
    const float* wk     = (const float*)d_in[7];
    const float* wv     = (const float*)d_in[8];
    const float* wg     = (const float*)d_in[9];
    const float* wo     = (const float*)d_in[10];
    float* out = (float*)d_out;
    char* ws = (char*)d_ws;

    unsigned short* SP  = (unsigned short*)(ws);                 // 16 MB bias [b][h][i][j]
    unsigned short* Qb  = (unsigned short*)(ws + 16777216);      // 2 MB (pre-scaled 0.125)
    unsigned short* Kb  = (unsigned short*)(ws + 18874368);      // 2 MB
    unsigned short* Vt  = (unsigned short*)(ws + 20971520);      // 2 MB [b][h][dh][n]
    unsigned short* Xg  = (unsigned short*)(ws + 23068672);      // 2 MB
    unsigned short* Og  = (unsigned short*)(ws + 25165824);      // 2 MB
    unsigned short* Wt  = (unsigned short*)(ws + 27262976);      // 3 MB [4*1024][384]
    unsigned short* Wot = (unsigned short*)(ws + 30408704);      // 0.75 MB [384][1024]
    unsigned short* GhG = (unsigned short*)(ws + 31195136);      // 4 KB  [16][128] bf16
    float* SsG          = (float*)(ws + 31199232);               // 64 B
    float* TsG          = (float*)(ws + 31199296);               // 64 B

    k_transpose_all<<<dim3(32, 32, 6), 256, 0, stream>>>(wq, wk, wv, wg, wo,
                                                         gamma, beta, wb,
                                                         Wt, Wot, GhG, SsG, TsG);
    k_bias<<<8192, 256, 0, stream>>>(pw, abb, GhG, SsG, TsG, SP);
    k_proj<<<dim3(8, 32), 256, 0, stream>>>(single, Wt, Qb, Kb, Vt, Xg);
    k_flash<<<dim3(8, 32), 256, 0, stream>>>(Qb, Kb, Vt, SP, Xg, Og);
    k_out<<<dim3(8, 3), 256, 0, stream>>>(Og, Wot, out);
}